// Round 12
// baseline (90.685 us; speedup 1.0000x reference)
//
#include <hip/hip_runtime.h>

typedef float  f32x4  __attribute__((ext_vector_type(4)));
typedef short  s16x8  __attribute__((ext_vector_type(8)));
typedef short  s16x4  __attribute__((ext_vector_type(4)));

#define NROWS (2048 * 128)
#define PASSES 2         // 16-row passes per wave; 4 waves x 2 x 16 = 128 rows/block
#define HS 104           // act LDS stride in shorts
#define EPSF 1e-8f

union Frag { s16x8 v; unsigned short u[8]; };

// fp32 -> bf16 RTNE (verified R3-R11, absmax 0.0)
__device__ __forceinline__ unsigned short f2bf(float f) {
    unsigned int u = __float_as_uint(f);
    u += 0x7fffu + ((u >> 16) & 1u);
    return (unsigned short)(u >> 16);
}

// ---------------------------------------------------------------------------
// Pre-kernel: repack weights to bf16 MFMA B-fragment order (unchanged).
// ws layout: [acc 1024][w1f 24576][b1 384][b2 320][b3 256][w2f 15360][w3f 12288]
// ---------------------------------------------------------------------------
__global__ void repack(const float* __restrict__ W1, const float* __restrict__ b1,
                       const float* __restrict__ W2, const float* __restrict__ b2,
                       const float* __restrict__ W3, const float* __restrict__ b3,
                       unsigned short* __restrict__ w1f, unsigned short* __restrict__ w2f,
                       unsigned short* __restrict__ w3f,
                       float* __restrict__ b1p, float* __restrict__ b2p,
                       float* __restrict__ b3p)
{
    const int b = blockIdx.x;
    const int l = threadIdx.x;      // 64 threads
    const int g = l >> 4, sl = l & 15;

    if (b < 24) {                   // W1: nt = b>>2, ks = b&3
        const int nt = b >> 2, ks = b & 3;
        const int o = nt * 16 + sl, kb = ks * 32 + g * 8;
        s16x8 v;
#pragma unroll
        for (int j = 0; j < 8; ++j) v[j] = (short)f2bf(W1[o * 128 + kb + j]);
        *(s16x8*)&w1f[b * 512 + l * 8] = v;
    } else if (b < 39) {            // W2 (out padded 72->80)
        const int f = b - 24, nt = f / 3, ks = f % 3;
        const int o = nt * 16 + sl, kb = ks * 32 + g * 8;
        s16x8 v;
#pragma unroll
        for (int j = 0; j < 8; ++j)
            v[j] = (short)((o < 72) ? f2bf(W2[o * 96 + kb + j]) : 0);
        *(s16x8*)&w2f[f * 512 + l * 8] = v;
    } else if (b < 51) {            // W3 (k padded 72->96)
        const int f = b - 39, nt = f / 3, ks = f % 3;
        const int o = nt * 16 + sl, kb = ks * 32 + g * 8;
        s16x8 v;
#pragma unroll
        for (int j = 0; j < 8; ++j)
            v[j] = (short)((kb + j < 72) ? f2bf(W3[o * 72 + kb + j]) : 0);
        *(s16x8*)&w3f[f * 512 + l * 8] = v;
    } else {                        // biases, zero-padded
        for (int i = l; i < 240; i += 64) {
            if (i < 96)       b1p[i] = b1[i];
            else if (i < 176) { int o = i - 96; b2p[o] = (o < 72) ? b2[o] : 0.f; }
            else              b3p[i - 176] = b3[i - 176];
        }
    }
}

// ---------------------------------------------------------------------------
// Main. R11 minus the register x-prefetch (xp[8] = 32 VGPR): R11's alloc was
// 192 (2 waves/EU). Live drops ~180 -> ~150, so alloc should land <= 170 ->
// 3 waves/EU = 12 waves/CU (+50% TLP). The cold per-pass x load (~1000 cyc
// HBM) is covered by the extra waves instead of by ILP-prefetch -- this is
// the direct test of "is the chain TLP-coverable". PASSES=2 (grid 2048) for
// finer residency streaming. LDS 39.9 KB (W1+biases 25.5 + act 13.3).
// lb(256,1): the only setting the 11-round record shows avoids the
// occupancy-heuristic VGPR clamp + spill.
// ---------------------------------------------------------------------------
__global__ __launch_bounds__(256, 1)
void mlp_main(const float* __restrict__ x,
              const f32x4* __restrict__ w1src,          // W1 frags + biases (1596 x 16 B)
              const unsigned short* __restrict__ w2f,   // 15 frags, global (L2-hot)
              const unsigned short* __restrict__ w3f,   // 12 frags, global (L2-hot)
              float* __restrict__ acc /* [65]: s[64], uu */)
{
    __shared__ __align__(16) unsigned char  wb[25536];        // W1 frags | b1 | b2 | b3
    __shared__ __align__(16) unsigned short act[4][16][HS];   // 13.3 KB wave-private
    __shared__ float sred[4][64];
    __shared__ float uured[4];

    const unsigned short* w1L = (const unsigned short*)wb;    // 24 frags
    const float* b1L = (const float*)(wb + 24576);            // 96
    const float* b2L = b1L + 96;                              // 80
    const float* b3L = b1L + 176;                             // 64

    const int tid  = threadIdx.x;
    const int lane = tid & 63;
    const int wv   = tid >> 6;
    const int g    = lane >> 4;
    const int sl   = lane & 15;

    // lane-fixed x base: row sl, cols g*8 (+ks*32)
    const float* xwave = x + ((size_t)(blockIdx.x * 4 + wv) * (16 * PASSES)) * 128
                         + sl * 128 + g * 8;

    // ---- stage W1 + biases to LDS (25536 B = 1596 f32x4) ----
    for (int i = tid; i < 1596; i += 256)
        ((f32x4*)wb)[i] = w1src[i];
    __syncthreads();

    float uu_part = 0.f;
    float s_part[4] = {0.f, 0.f, 0.f, 0.f};

#pragma unroll 1        // keep passes as a rolled loop (bounds live state)
    for (int p = 0; p < PASSES; ++p) {
        // ---- load this pass's x directly (8 x dwordx4; TLP hides the miss) ----
        const float* xw = xwave + (size_t)p * (16 * 128);
        f32x4 t[8];
#pragma unroll
        for (int ks = 0; ks < 4; ++ks) {
            t[ks * 2 + 0] = *(const f32x4*)(xw + ks * 32);
            t[ks * 2 + 1] = *(const f32x4*)(xw + ks * 32 + 4);
        }
        Frag A1[4];
#pragma unroll
        for (int ks = 0; ks < 4; ++ks)
#pragma unroll
            for (int j = 0; j < 4; ++j) {
                A1[ks].u[j]     = f2bf(t[ks * 2 + 0][j]);
                A1[ks].u[4 + j] = f2bf(t[ks * 2 + 1][j]);
            }

        // ================= layer 1: 128 -> 96 (W1 from LDS) =================
        f32x4 D1[6];
#pragma unroll
        for (int nt = 0; nt < 6; ++nt) {
            const float bb = b1L[nt * 16 + sl];
            D1[nt] = (f32x4){bb, bb, bb, bb};
        }
#pragma unroll
        for (int ks = 0; ks < 4; ++ks)
#pragma unroll
            for (int nt = 0; nt < 6; ++nt) {
                const s16x8 B = *(const s16x8*)&w1L[(nt * 4 + ks) * 512 + lane * 8];
                D1[nt] = __builtin_amdgcn_mfma_f32_16x16x32_bf16(A1[ks].v, B, D1[nt], 0, 0, 0);
            }
        // relu + write h1[sample = g*4+r][feat = nt*16+sl] (wave-private)
#pragma unroll
        for (int nt = 0; nt < 6; ++nt)
#pragma unroll
            for (int r = 0; r < 4; ++r)
                act[wv][g * 4 + r][nt * 16 + sl] = f2bf(fmaxf(D1[nt][r], 0.f));

        // layer-2 A-frags: feats 0..95 of sample sl
        Frag A2[3];
#pragma unroll
        for (int ks = 0; ks < 3; ++ks)
            A2[ks].v = *(const s16x8*)&act[wv][sl][ks * 32 + g * 8];

        // zero pad feats 80..95 for the h2 tile (read by L3 ks=2)
        {
            const s16x4 z = (s16x4){0, 0, 0, 0};
            *(s16x4*)&act[wv][sl][80 + g * 4] = z;
        }

        // ============== layer 2: 96 -> 72 (pad 80; W2 from L2) ==============
        f32x4 D2[5];
#pragma unroll
        for (int nt = 0; nt < 5; ++nt) {
            const float bb = b2L[nt * 16 + sl];
            D2[nt] = (f32x4){bb, bb, bb, bb};
        }
#pragma unroll
        for (int ks = 0; ks < 3; ++ks)
#pragma unroll
            for (int nt = 0; nt < 5; ++nt) {
                const s16x8 B = *(const s16x8*)&w2f[(nt * 3 + ks) * 512 + lane * 8];
                D2[nt] = __builtin_amdgcn_mfma_f32_16x16x32_bf16(A2[ks].v, B, D2[nt], 0, 0, 0);
            }
#pragma unroll
        for (int nt = 0; nt < 5; ++nt)
#pragma unroll
            for (int r = 0; r < 4; ++r)
                act[wv][g * 4 + r][nt * 16 + sl] = f2bf(fmaxf(D2[nt][r], 0.f));

        // layer-3 A-frags: h2 feats 0..95 (72..95 structurally zero)
        Frag A3[3];
#pragma unroll
        for (int ks = 0; ks < 3; ++ks)
            A3[ks].v = *(const s16x8*)&act[wv][sl][ks * 32 + g * 8];

        // ============== layer 3: 72 (pad 96) -> 64 (W3 from L2) ==============
        f32x4 D3[4];
#pragma unroll
        for (int nt = 0; nt < 4; ++nt) {
            const float bb = b3L[nt * 16 + sl];
            D3[nt] = (f32x4){bb, bb, bb, bb};
        }
#pragma unroll
        for (int ks = 0; ks < 3; ++ks)
#pragma unroll
            for (int nt = 0; nt < 4; ++nt) {
                const s16x8 B = *(const s16x8*)&w3f[(nt * 3 + ks) * 512 + lane * 8];
                D3[nt] = __builtin_amdgcn_mfma_f32_16x16x32_bf16(A3[ks].v, B, D3[nt], 0, 0, 0);
            }

        // ===== epilogue: row norm; accumulate s/uu across passes =====
        float ffr[4];
#pragma unroll
        for (int r = 0; r < 4; ++r) {
            float a = 0.f;
#pragma unroll
            for (int nt = 0; nt < 4; ++nt)
                a = fmaf(D3[nt][r], D3[nt][r], a);
            ffr[r] = a;
        }
#pragma unroll
        for (int r = 0; r < 4; ++r) {
            ffr[r] += __shfl_xor(ffr[r], 1, 64);
            ffr[r] += __shfl_xor(ffr[r], 2, 64);
            ffr[r] += __shfl_xor(ffr[r], 4, 64);
            ffr[r] += __shfl_xor(ffr[r], 8, 64);
        }
        float inv[4];
#pragma unroll
        for (int r = 0; r < 4; ++r) {
            inv[r] = 1.f / fmaxf(sqrtf(ffr[r]), EPSF);
            uu_part = fmaf(ffr[r] * inv[r], inv[r], uu_part);  // dup x16 over sl
        }
#pragma unroll
        for (int nt = 0; nt < 4; ++nt)
#pragma unroll
            for (int r = 0; r < 4; ++r)
                s_part[nt] = fmaf(D3[nt][r], inv[r], s_part[nt]);
    }

    // cross-g reduction (once, after all passes)
#pragma unroll
    for (int nt = 0; nt < 4; ++nt) {
        s_part[nt] += __shfl_xor(s_part[nt], 16, 64);
        s_part[nt] += __shfl_xor(s_part[nt], 32, 64);
    }
    uu_part += __shfl_xor(uu_part, 16, 64);
    uu_part += __shfl_xor(uu_part, 32, 64);

    if (g == 0) {
#pragma unroll
        for (int nt = 0; nt < 4; ++nt) sred[wv][nt * 16 + sl] = s_part[nt];
    }
    if (lane == 0) uured[wv] = uu_part * 0.0625f;
    __syncthreads();

    if (tid < 64) {
        const float t = sred[0][tid] + sred[1][tid] + sred[2][tid] + sred[3][tid];
        atomicAdd(&acc[tid], t);
    }
    if (tid == 0)
        atomicAdd(&acc[64], uured[0] + uured[1] + uured[2] + uured[3]);
}

__global__ void finalize_k(const float* __restrict__ acc, float* __restrict__ out)
{
    float s = acc[threadIdx.x];
    float d = s * s;
#pragma unroll
    for (int off = 32; off > 0; off >>= 1)
        d += __shfl_xor(d, off, 64);
    if (threadIdx.x == 0)
        out[0] = 0.5f * (d - acc[64]) / (float)NROWS;
}

extern "C" void kernel_launch(void* const* d_in, const int* in_sizes, int n_in,
                              void* d_out, int out_size, void* d_ws, size_t ws_size,
                              hipStream_t stream)
{
    const float* x  = (const float*)d_in[0];
    const float* W1 = (const float*)d_in[1];
    const float* b1 = (const float*)d_in[2];
    const float* W2 = (const float*)d_in[3];
    const float* b2 = (const float*)d_in[4];
    const float* W3 = (const float*)d_in[5];
    const float* b3 = (const float*)d_in[6];

    char* ws = (char*)d_ws;
    // layout: [acc 1024][w1f 24576][b1 384][b2 320][b3 256][w2f 15360][w3f 12288]
    float*          acc = (float*)ws;
    unsigned short* w1f = (unsigned short*)(ws + 1024);
    float*          b1p = (float*)(ws + 25600);
    float*          b2p = (float*)(ws + 25984);
    float*          b3p = (float*)(ws + 26304);
    unsigned short* w2f = (unsigned short*)(ws + 26560);
    unsigned short* w3f = (unsigned short*)(ws + 41920);

    hipMemsetAsync(acc, 0, 1024, stream);
    repack<<<52, 64, 0, stream>>>(W1, b1, W2, b2, W3, b3, w1f, w2f, w3f, b1p, b2p, b3p);
    // 2048 blocks x 4 waves x 2 passes x 16 rows = 262144 rows
    mlp_main<<<NROWS / (4 * PASSES * 16), 256, 0, stream>>>(
        x, (const f32x4*)(ws + 1024), w2f, w3f, acc);
    finalize_k<<<1, 64, 0, stream>>>(acc, (float*)d_out);
}

// Round 13
// 59.195 us; speedup vs baseline: 1.5320x; 1.5320x over previous
//
#include <hip/hip_runtime.h>

typedef float  f32x4  __attribute__((ext_vector_type(4)));
typedef short  s16x8  __attribute__((ext_vector_type(8)));
typedef short  s16x4  __attribute__((ext_vector_type(4)));

#define NROWS (2048 * 128)
#define PASSES 8         // 16-row passes per wave; 512 blocks x 4 waves x 8 x 16
#define HS 104           // act LDS stride in shorts
#define EPSF 1e-8f

union Frag { s16x8 v; unsigned short u[8]; };

// fp32 -> bf16 RTNE (verified R3-R12, absmax 0.0)
__device__ __forceinline__ unsigned short f2bf(float f) {
    unsigned int u = __float_as_uint(f);
    u += 0x7fffu + ((u >> 16) & 1u);
    return (unsigned short)(u >> 16);
}

// ---------------------------------------------------------------------------
// Pre-kernel: repack weights to bf16 MFMA B-fragment order (unchanged).
// ws layout: [acc 1024][w1f 24576][b1 384][b2 320][b3 256][w2f 15360][w3f 12288]
// ---------------------------------------------------------------------------
__global__ void repack(const float* __restrict__ W1, const float* __restrict__ b1,
                       const float* __restrict__ W2, const float* __restrict__ b2,
                       const float* __restrict__ W3, const float* __restrict__ b3,
                       unsigned short* __restrict__ w1f, unsigned short* __restrict__ w2f,
                       unsigned short* __restrict__ w3f,
                       float* __restrict__ b1p, float* __restrict__ b2p,
                       float* __restrict__ b3p)
{
    const int b = blockIdx.x;
    const int l = threadIdx.x;      // 64 threads
    const int g = l >> 4, sl = l & 15;

    if (b < 24) {                   // W1: nt = b>>2, ks = b&3
        const int nt = b >> 2, ks = b & 3;
        const int o = nt * 16 + sl, kb = ks * 32 + g * 8;
        s16x8 v;
#pragma unroll
        for (int j = 0; j < 8; ++j) v[j] = (short)f2bf(W1[o * 128 + kb + j]);
        *(s16x8*)&w1f[b * 512 + l * 8] = v;
    } else if (b < 39) {            // W2 (out padded 72->80)
        const int f = b - 24, nt = f / 3, ks = f % 3;
        const int o = nt * 16 + sl, kb = ks * 32 + g * 8;
        s16x8 v;
#pragma unroll
        for (int j = 0; j < 8; ++j)
            v[j] = (short)((o < 72) ? f2bf(W2[o * 96 + kb + j]) : 0);
        *(s16x8*)&w2f[f * 512 + l * 8] = v;
    } else if (b < 51) {            // W3 (k padded 72->96)
        const int f = b - 39, nt = f / 3, ks = f % 3;
        const int o = nt * 16 + sl, kb = ks * 32 + g * 8;
        s16x8 v;
#pragma unroll
        for (int j = 0; j < 8; ++j)
            v[j] = (short)((kb + j < 72) ? f2bf(W3[o * 72 + kb + j]) : 0);
        *(s16x8*)&w3f[f * 512 + l * 8] = v;
    } else {                        // biases, zero-padded
        for (int i = l; i < 240; i += 64) {
            if (i < 96)       b1p[i] = b1[i];
            else if (i < 176) { int o = i - 96; b2p[o] = (o < 72) ? b2[o] : 0.f; }
            else              b3p[i - 176] = b3[i - 176];
        }
    }
}

// ---------------------------------------------------------------------------
// Main. LITTLE'S-LAW FIX: R5-R12 all ran the x stream at ~1.4 TB/s because a
// wave only ever had 16 loads (256 B) in flight: 512 KB device-wide / 375 ns
// HBM latency = 1.37 TB/s = measured. This version stages each wave's 8 KB
// x tile via 8x global_load_lds(width=16) -- in-flight bytes live in LDS,
// not VGPRs -- giving ~45 KB/CU in flight -> HBM-saturated (~6 TB/s).
// Swizzle (both-sides, rule: inverse-swz global source + swz read,
// byte ^= ((row&7)<<4)) keeps the stride-512B readback 2-way conflict-free.
// LDS: W1+b 25.5K + act 13.3K + xbuf 32K = 71K -> 2 blocks/CU, 8 waves.
// W2/W3 from L2 (R11-proven). lb(256,1) (only non-spilling setting).
// ---------------------------------------------------------------------------
__global__ __launch_bounds__(256, 1)
void mlp_main(const float* __restrict__ x,
              const f32x4* __restrict__ w1src,          // W1 frags + biases (1596 x 16 B)
              const unsigned short* __restrict__ w2f,   // 15 frags, global (L2-hot)
              const unsigned short* __restrict__ w3f,   // 12 frags, global (L2-hot)
              float* __restrict__ acc /* [65]: s[64], uu */)
{
    __shared__ __align__(16) unsigned char  wb[25536];        // W1 frags | b1 | b2 | b3
    __shared__ __align__(16) float          xbuf[4][2048];    // 32 KB: 8 KB/wave x tile
    __shared__ __align__(16) unsigned short act[4][16][HS];   // 13.3 KB wave-private
    __shared__ float sred[4][64];
    __shared__ float uured[4];

    const unsigned short* w1L = (const unsigned short*)wb;    // 24 frags
    const float* b1L = (const float*)(wb + 24576);            // 96
    const float* b2L = b1L + 96;                              // 80
    const float* b3L = b1L + 176;                             // 64

    const int tid  = threadIdx.x;
    const int lane = tid & 63;
    const int wv   = tid >> 6;
    const int g    = lane >> 4;
    const int sl   = lane & 15;
    const int wave_gid = blockIdx.x * 4 + wv;     // 0..2047; wave owns 128 rows

    // ---- async stage of pass p's 16-row x tile (8 KB) into this wave's buf.
    // LDS dest linear; global SOURCE pre-swizzled so that LDS[off] holds
    // x[off ^ s(off)], s(off) = ((off>>9)&7)<<4  (involution; bits 4-6 only).
    auto stage = [&](int p) {
        const char* tb = (const char*)x
                       + ((size_t)wave_gid * 128 + (size_t)p * 16) * 512;
        float* dst = &xbuf[wv][0];
#pragma unroll
        for (int c = 0; c < 8; ++c) {
            const unsigned off = (unsigned)(c * 1024 + lane * 16);
            const unsigned so  = off ^ (((off >> 9) & 7u) << 4);
            __builtin_amdgcn_global_load_lds(
                (const __attribute__((address_space(1))) void*)(tb + so),
                (__attribute__((address_space(3))) void*)(dst + c * 256),
                16, 0, 0);
        }
    };

    stage(0);                                   // in flight during W1 staging

    // ---- stage W1 + biases to LDS (25536 B = 1596 f32x4) ----
    for (int i = tid; i < 1596; i += 256)
        ((f32x4*)wb)[i] = w1src[i];
    __syncthreads();                            // also drains stage(0) vmcnt

    float uu_part = 0.f;
    float s_part[4] = {0.f, 0.f, 0.f, 0.f};

#pragma unroll 1
    for (int p = 0; p < PASSES; ++p) {
        // wait for this pass's staged tile
        asm volatile("s_waitcnt vmcnt(0)" ::: "memory");
        __builtin_amdgcn_sched_barrier(0);

        // ---- read x from LDS (swizzled) -> regs, cvt to A-frags ----
        const char* xb = (const char*)&xbuf[wv][0];
        const unsigned sw = (unsigned)((sl & 7) << 4);
        f32x4 t[8];
#pragma unroll
        for (int ks = 0; ks < 4; ++ks)
#pragma unroll
            for (int h = 0; h < 2; ++h)
                t[ks * 2 + h] = *(const f32x4*)(
                    xb + sl * 512 + ks * 128 + (((unsigned)(g * 32 + h * 16)) ^ sw));
        Frag A1[4];
#pragma unroll
        for (int ks = 0; ks < 4; ++ks)
#pragma unroll
            for (int j = 0; j < 4; ++j) {
                A1[ks].u[j]     = f2bf(t[ks * 2 + 0][j]);
                A1[ks].u[4 + j] = f2bf(t[ks * 2 + 1][j]);
            }

        // buffer free: issue next pass's stage; overlaps L1-L3 compute below
        __builtin_amdgcn_sched_barrier(0);
        if (p + 1 < PASSES) stage(p + 1);

        // ================= layer 1: 128 -> 96 (W1 from LDS) =================
        f32x4 D1[6];
#pragma unroll
        for (int nt = 0; nt < 6; ++nt) {
            const float bb = b1L[nt * 16 + sl];
            D1[nt] = (f32x4){bb, bb, bb, bb};
        }
#pragma unroll
        for (int ks = 0; ks < 4; ++ks)
#pragma unroll
            for (int nt = 0; nt < 6; ++nt) {
                const s16x8 B = *(const s16x8*)&w1L[(nt * 4 + ks) * 512 + lane * 8];
                D1[nt] = __builtin_amdgcn_mfma_f32_16x16x32_bf16(A1[ks].v, B, D1[nt], 0, 0, 0);
            }
#pragma unroll
        for (int nt = 0; nt < 6; ++nt)
#pragma unroll
            for (int r = 0; r < 4; ++r)
                act[wv][g * 4 + r][nt * 16 + sl] = f2bf(fmaxf(D1[nt][r], 0.f));

        // layer-2 A-frags: feats 0..95 of sample sl
        Frag A2[3];
#pragma unroll
        for (int ks = 0; ks < 3; ++ks)
            A2[ks].v = *(const s16x8*)&act[wv][sl][ks * 32 + g * 8];

        // zero pad feats 80..95 for the h2 tile (read by L3 ks=2)
        {
            const s16x4 z = (s16x4){0, 0, 0, 0};
            *(s16x4*)&act[wv][sl][80 + g * 4] = z;
        }

        // ============== layer 2: 96 -> 72 (pad 80; W2 from L2) ==============
        f32x4 D2[5];
#pragma unroll
        for (int nt = 0; nt < 5; ++nt) {
            const float bb = b2L[nt * 16 + sl];
            D2[nt] = (f32x4){bb, bb, bb, bb};
        }
#pragma unroll
        for (int ks = 0; ks < 3; ++ks)
#pragma unroll
            for (int nt = 0; nt < 5; ++nt) {
                const s16x8 B = *(const s16x8*)&w2f[(nt * 3 + ks) * 512 + lane * 8];
                D2[nt] = __builtin_amdgcn_mfma_f32_16x16x32_bf16(A2[ks].v, B, D2[nt], 0, 0, 0);
            }
#pragma unroll
        for (int nt = 0; nt < 5; ++nt)
#pragma unroll
            for (int r = 0; r < 4; ++r)
                act[wv][g * 4 + r][nt * 16 + sl] = f2bf(fmaxf(D2[nt][r], 0.f));

        // layer-3 A-frags: h2 feats 0..95 (72..95 structurally zero)
        Frag A3[3];
#pragma unroll
        for (int ks = 0; ks < 3; ++ks)
            A3[ks].v = *(const s16x8*)&act[wv][sl][ks * 32 + g * 8];

        // ============== layer 3: 72 (pad 96) -> 64 (W3 from L2) ==============
        f32x4 D3[4];
#pragma unroll
        for (int nt = 0; nt < 4; ++nt) {
            const float bb = b3L[nt * 16 + sl];
            D3[nt] = (f32x4){bb, bb, bb, bb};
        }
#pragma unroll
        for (int ks = 0; ks < 3; ++ks)
#pragma unroll
            for (int nt = 0; nt < 4; ++nt) {
                const s16x8 B = *(const s16x8*)&w3f[(nt * 3 + ks) * 512 + lane * 8];
                D3[nt] = __builtin_amdgcn_mfma_f32_16x16x32_bf16(A3[ks].v, B, D3[nt], 0, 0, 0);
            }

        // ===== epilogue: row norm; accumulate s/uu across passes =====
        float ffr[4];
#pragma unroll
        for (int r = 0; r < 4; ++r) {
            float a = 0.f;
#pragma unroll
            for (int nt = 0; nt < 4; ++nt)
                a = fmaf(D3[nt][r], D3[nt][r], a);
            ffr[r] = a;
        }
#pragma unroll
        for (int r = 0; r < 4; ++r) {
            ffr[r] += __shfl_xor(ffr[r], 1, 64);
            ffr[r] += __shfl_xor(ffr[r], 2, 64);
            ffr[r] += __shfl_xor(ffr[r], 4, 64);
            ffr[r] += __shfl_xor(ffr[r], 8, 64);
        }
        float inv[4];
#pragma unroll
        for (int r = 0; r < 4; ++r) {
            inv[r] = 1.f / fmaxf(sqrtf(ffr[r]), EPSF);
            uu_part = fmaf(ffr[r] * inv[r], inv[r], uu_part);  // dup x16 over sl
        }
#pragma unroll
        for (int nt = 0; nt < 4; ++nt)
#pragma unroll
            for (int r = 0; r < 4; ++r)
                s_part[nt] = fmaf(D3[nt][r], inv[r], s_part[nt]);
    }

    // cross-g reduction (once, after all passes)
#pragma unroll
    for (int nt = 0; nt < 4; ++nt) {
        s_part[nt] += __shfl_xor(s_part[nt], 16, 64);
        s_part[nt] += __shfl_xor(s_part[nt], 32, 64);
    }
    uu_part += __shfl_xor(uu_part, 16, 64);
    uu_part += __shfl_xor(uu_part, 32, 64);

    if (g == 0) {
#pragma unroll
        for (int nt = 0; nt < 4; ++nt) sred[wv][nt * 16 + sl] = s_part[nt];
    }
    if (lane == 0) uured[wv] = uu_part * 0.0625f;
    __syncthreads();

    if (tid < 64) {
        const float t = sred[0][tid] + sred[1][tid] + sred[2][tid] + sred[3][tid];
        atomicAdd(&acc[tid], t);
    }
    if (tid == 0)
        atomicAdd(&acc[64], uured[0] + uured[1] + uured[2] + uured[3]);
}

__global__ void finalize_k(const float* __restrict__ acc, float* __restrict__ out)
{
    float s = acc[threadIdx.x];
    float d = s * s;
#pragma unroll
    for (int off = 32; off > 0; off >>= 1)
        d += __shfl_xor(d, off, 64);
    if (threadIdx.x == 0)
        out[0] = 0.5f * (d - acc[64]) / (float)NROWS;
}

extern "C" void kernel_launch(void* const* d_in, const int* in_sizes, int n_in,
                              void* d_out, int out_size, void* d_ws, size_t ws_size,
                              hipStream_t stream)
{
    const float* x  = (const float*)d_in[0];
    const float* W1 = (const float*)d_in[1];
    const float* b1 = (const float*)d_in[2];
    const float* W2 = (const float*)d_in[3];
    const float* b2 = (const float*)d_in[4];
    const float* W3 = (const float*)d_in[5];
    const float* b3 = (const float*)d_in[6];

    char* ws = (char*)d_ws;
    // layout: [acc 1024][w1f 24576][b1 384][b2 320][b3 256][w2f 15360][w3f 12288]
    float*          acc = (float*)ws;
    unsigned short* w1f = (unsigned short*)(ws + 1024);
    float*          b1p = (float*)(ws + 25600);
    float*          b2p = (float*)(ws + 25984);
    float*          b3p = (float*)(ws + 26304);
    unsigned short* w2f = (unsigned short*)(ws + 26560);
    unsigned short* w3f = (unsigned short*)(ws + 41920);

    hipMemsetAsync(acc, 0, 1024, stream);
    repack<<<52, 64, 0, stream>>>(W1, b1, W2, b2, W3, b3, w1f, w2f, w3f, b1p, b2p, b3p);
    // 512 blocks x 4 waves x 8 passes x 16 rows = 262144 rows
    mlp_main<<<NROWS / (4 * PASSES * 16), 256, 0, stream>>>(
        x, (const f32x4*)(ws + 1024), w2f, w3f, acc);
    finalize_k<<<1, 64, 0, stream>>>(acc, (float*)d_out);
}

// Round 14
// 54.908 us; speedup vs baseline: 1.6516x; 1.0781x over previous
//
#include <hip/hip_runtime.h>

typedef float  f32x4  __attribute__((ext_vector_type(4)));
typedef short  s16x8  __attribute__((ext_vector_type(8)));
typedef short  s16x4  __attribute__((ext_vector_type(4)));

#define NROWS (2048 * 128)
#define PASSES 8         // 16-row passes per wave; 512 blocks x 4 waves x 8 x 16
#define HS 104           // act LDS stride in shorts
#define EPSF 1e-8f

union Frag { s16x8 v; unsigned short u[8]; };

// fp32 -> bf16 RTNE (verified R3-R13, absmax 0.0)
__device__ __forceinline__ unsigned short f2bf(float f) {
    unsigned int u = __float_as_uint(f);
    u += 0x7fffu + ((u >> 16) & 1u);
    return (unsigned short)(u >> 16);
}

// ---------------------------------------------------------------------------
// Pre-kernel: repack weights to bf16 MFMA B-fragment order (unchanged).
// ws layout: [acc 1024][w1f 24576][b1 384][b2 320][b3 256][w2f 15360][w3f 12288]
// ---------------------------------------------------------------------------
__global__ void repack(const float* __restrict__ W1, const float* __restrict__ b1,
                       const float* __restrict__ W2, const float* __restrict__ b2,
                       const float* __restrict__ W3, const float* __restrict__ b3,
                       unsigned short* __restrict__ w1f, unsigned short* __restrict__ w2f,
                       unsigned short* __restrict__ w3f,
                       float* __restrict__ b1p, float* __restrict__ b2p,
                       float* __restrict__ b3p)
{
    const int b = blockIdx.x;
    const int l = threadIdx.x;      // 64 threads
    const int g = l >> 4, sl = l & 15;

    if (b < 24) {                   // W1: nt = b>>2, ks = b&3
        const int nt = b >> 2, ks = b & 3;
        const int o = nt * 16 + sl, kb = ks * 32 + g * 8;
        s16x8 v;
#pragma unroll
        for (int j = 0; j < 8; ++j) v[j] = (short)f2bf(W1[o * 128 + kb + j]);
        *(s16x8*)&w1f[b * 512 + l * 8] = v;
    } else if (b < 39) {            // W2 (out padded 72->80)
        const int f = b - 24, nt = f / 3, ks = f % 3;
        const int o = nt * 16 + sl, kb = ks * 32 + g * 8;
        s16x8 v;
#pragma unroll
        for (int j = 0; j < 8; ++j)
            v[j] = (short)((o < 72) ? f2bf(W2[o * 96 + kb + j]) : 0);
        *(s16x8*)&w2f[f * 512 + l * 8] = v;
    } else if (b < 51) {            // W3 (k padded 72->96)
        const int f = b - 39, nt = f / 3, ks = f % 3;
        const int o = nt * 16 + sl, kb = ks * 32 + g * 8;
        s16x8 v;
#pragma unroll
        for (int j = 0; j < 8; ++j)
            v[j] = (short)((kb + j < 72) ? f2bf(W3[o * 72 + kb + j]) : 0);
        *(s16x8*)&w3f[f * 512 + l * 8] = v;
    } else {                        // biases, zero-padded
        for (int i = l; i < 240; i += 64) {
            if (i < 96)       b1p[i] = b1[i];
            else if (i < 176) { int o = i - 96; b2p[o] = (o < 72) ? b2[o] : 0.f; }
            else              b3p[i - 176] = b3[i - 176];
        }
    }
}

// ---------------------------------------------------------------------------
// Main. R13 (deep-in-flight x staging via global_load_lds + swizzle) plus:
// W2/W3 B-fragments are LOOP-INVARIANT -> hoisted into registers before the
// pass loop (27 frags x 4 VGPR = 108). Deletes 27 L2 loads (~200-500 cyc
// each) and ~440 MB of repeated L2 traffic from the 8-pass loop. VGPR math:
// 192 -> ~230-256, still 2 waves/EU (floor(512/256)=2) -> zero occupancy
// cost. W1 stays in LDS (adding its 96 regs would exceed the live budget).
// lb(256,1): the only allocator setting that doesn't clamp+spill (R1-R12).
// ---------------------------------------------------------------------------
__global__ __launch_bounds__(256, 1)
void mlp_main(const float* __restrict__ x,
              const f32x4* __restrict__ w1src,          // W1 frags + biases (1596 x 16 B)
              const unsigned short* __restrict__ w2f,   // 15 frags (hoisted to regs)
              const unsigned short* __restrict__ w3f,   // 12 frags (hoisted to regs)
              float* __restrict__ acc /* [65]: s[64], uu */)
{
    __shared__ __align__(16) unsigned char  wb[25536];        // W1 frags | b1 | b2 | b3
    __shared__ __align__(16) float          xbuf[4][2048];    // 32 KB: 8 KB/wave x tile
    __shared__ __align__(16) unsigned short act[4][16][HS];   // 13.3 KB wave-private
    __shared__ float sred[4][64];
    __shared__ float uured[4];

    const unsigned short* w1L = (const unsigned short*)wb;    // 24 frags
    const float* b1L = (const float*)(wb + 24576);            // 96
    const float* b2L = b1L + 96;                              // 80
    const float* b3L = b1L + 176;                             // 64

    const int tid  = threadIdx.x;
    const int lane = tid & 63;
    const int wv   = tid >> 6;
    const int g    = lane >> 4;
    const int sl   = lane & 15;
    const int wave_gid = blockIdx.x * 4 + wv;     // 0..2047; wave owns 128 rows

    // ---- async stage of pass p's 16-row x tile (8 KB) into this wave's buf.
    // LDS dest linear; global SOURCE pre-swizzled: LDS[off] holds
    // x[off ^ s(off)], s(off) = ((off>>9)&7)<<4 (involution; bits 4-6 only).
    auto stage = [&](int p) {
        const char* tb = (const char*)x
                       + ((size_t)wave_gid * 128 + (size_t)p * 16) * 512;
        float* dst = &xbuf[wv][0];
#pragma unroll
        for (int c = 0; c < 8; ++c) {
            const unsigned off = (unsigned)(c * 1024 + lane * 16);
            const unsigned so  = off ^ (((off >> 9) & 7u) << 4);
            __builtin_amdgcn_global_load_lds(
                (const __attribute__((address_space(1))) void*)(tb + so),
                (__attribute__((address_space(3))) void*)(dst + c * 256),
                16, 0, 0);
        }
    };

    stage(0);                                   // in flight during W1 staging

    // ---- stage W1 + biases to LDS (25536 B = 1596 f32x4) ----
    for (int i = tid; i < 1596; i += 256)
        ((f32x4*)wb)[i] = w1src[i];

    // ---- hoist W2/W3 fragments into registers (loop-invariant) ----
    Frag W2r[5][3], W3r[4][3];
#pragma unroll
    for (int nt = 0; nt < 5; ++nt)
#pragma unroll
        for (int ks = 0; ks < 3; ++ks)
            W2r[nt][ks].v = *(const s16x8*)&w2f[(nt * 3 + ks) * 512 + lane * 8];
#pragma unroll
    for (int nt = 0; nt < 4; ++nt)
#pragma unroll
        for (int ks = 0; ks < 3; ++ks)
            W3r[nt][ks].v = *(const s16x8*)&w3f[(nt * 3 + ks) * 512 + lane * 8];

    __syncthreads();                            // weights visible; stage(0) drained

    float uu_part = 0.f;
    float s_part[4] = {0.f, 0.f, 0.f, 0.f};

#pragma unroll 1
    for (int p = 0; p < PASSES; ++p) {
        // wait for this pass's staged tile
        asm volatile("s_waitcnt vmcnt(0)" ::: "memory");
        __builtin_amdgcn_sched_barrier(0);

        // ---- read x from LDS (swizzled) -> regs, cvt to A-frags ----
        const char* xb = (const char*)&xbuf[wv][0];
        const unsigned sw = (unsigned)((sl & 7) << 4);
        f32x4 t[8];
#pragma unroll
        for (int ks = 0; ks < 4; ++ks)
#pragma unroll
            for (int h = 0; h < 2; ++h)
                t[ks * 2 + h] = *(const f32x4*)(
                    xb + sl * 512 + ks * 128 + (((unsigned)(g * 32 + h * 16)) ^ sw));
        Frag A1[4];
#pragma unroll
        for (int ks = 0; ks < 4; ++ks)
#pragma unroll
            for (int j = 0; j < 4; ++j) {
                A1[ks].u[j]     = f2bf(t[ks * 2 + 0][j]);
                A1[ks].u[4 + j] = f2bf(t[ks * 2 + 1][j]);
            }

        // buffer free: issue next pass's stage; overlaps compute below
        __builtin_amdgcn_sched_barrier(0);
        if (p + 1 < PASSES) stage(p + 1);

        // ================= layer 1: 128 -> 96 (W1 from LDS) =================
        f32x4 D1[6];
#pragma unroll
        for (int nt = 0; nt < 6; ++nt) {
            const float bb = b1L[nt * 16 + sl];
            D1[nt] = (f32x4){bb, bb, bb, bb};
        }
#pragma unroll
        for (int ks = 0; ks < 4; ++ks)
#pragma unroll
            for (int nt = 0; nt < 6; ++nt) {
                const s16x8 B = *(const s16x8*)&w1L[(nt * 4 + ks) * 512 + lane * 8];
                D1[nt] = __builtin_amdgcn_mfma_f32_16x16x32_bf16(A1[ks].v, B, D1[nt], 0, 0, 0);
            }
#pragma unroll
        for (int nt = 0; nt < 6; ++nt)
#pragma unroll
            for (int r = 0; r < 4; ++r)
                act[wv][g * 4 + r][nt * 16 + sl] = f2bf(fmaxf(D1[nt][r], 0.f));

        // layer-2 A-frags: feats 0..95 of sample sl
        Frag A2[3];
#pragma unroll
        for (int ks = 0; ks < 3; ++ks)
            A2[ks].v = *(const s16x8*)&act[wv][sl][ks * 32 + g * 8];

        // zero pad feats 80..95 for the h2 tile (read by L3 ks=2)
        {
            const s16x4 z = (s16x4){0, 0, 0, 0};
            *(s16x4*)&act[wv][sl][80 + g * 4] = z;
        }

        // ============ layer 2: 96 -> 72 (pad 80; W2 from REGISTERS) ============
        f32x4 D2[5];
#pragma unroll
        for (int nt = 0; nt < 5; ++nt) {
            const float bb = b2L[nt * 16 + sl];
            D2[nt] = (f32x4){bb, bb, bb, bb};
        }
#pragma unroll
        for (int ks = 0; ks < 3; ++ks)
#pragma unroll
            for (int nt = 0; nt < 5; ++nt)
                D2[nt] = __builtin_amdgcn_mfma_f32_16x16x32_bf16(A2[ks].v, W2r[nt][ks].v, D2[nt], 0, 0, 0);
#pragma unroll
        for (int nt = 0; nt < 5; ++nt)
#pragma unroll
            for (int r = 0; r < 4; ++r)
                act[wv][g * 4 + r][nt * 16 + sl] = f2bf(fmaxf(D2[nt][r], 0.f));

        // layer-3 A-frags: h2 feats 0..95 (72..95 structurally zero)
        Frag A3[3];
#pragma unroll
        for (int ks = 0; ks < 3; ++ks)
            A3[ks].v = *(const s16x8*)&act[wv][sl][ks * 32 + g * 8];

        // ============ layer 3: 72 (pad 96) -> 64 (W3 from REGISTERS) ============
        f32x4 D3[4];
#pragma unroll
        for (int nt = 0; nt < 4; ++nt) {
            const float bb = b3L[nt * 16 + sl];
            D3[nt] = (f32x4){bb, bb, bb, bb};
        }
#pragma unroll
        for (int ks = 0; ks < 3; ++ks)
#pragma unroll
            for (int nt = 0; nt < 4; ++nt)
                D3[nt] = __builtin_amdgcn_mfma_f32_16x16x32_bf16(A3[ks].v, W3r[nt][ks].v, D3[nt], 0, 0, 0);

        // ===== epilogue: row norm; accumulate s/uu across passes =====
        float ffr[4];
#pragma unroll
        for (int r = 0; r < 4; ++r) {
            float a = 0.f;
#pragma unroll
            for (int nt = 0; nt < 4; ++nt)
                a = fmaf(D3[nt][r], D3[nt][r], a);
            ffr[r] = a;
        }
#pragma unroll
        for (int r = 0; r < 4; ++r) {
            ffr[r] += __shfl_xor(ffr[r], 1, 64);
            ffr[r] += __shfl_xor(ffr[r], 2, 64);
            ffr[r] += __shfl_xor(ffr[r], 4, 64);
            ffr[r] += __shfl_xor(ffr[r], 8, 64);
        }
        float inv[4];
#pragma unroll
        for (int r = 0; r < 4; ++r) {
            inv[r] = 1.f / fmaxf(sqrtf(ffr[r]), EPSF);
            uu_part = fmaf(ffr[r] * inv[r], inv[r], uu_part);  // dup x16 over sl
        }
#pragma unroll
        for (int nt = 0; nt < 4; ++nt)
#pragma unroll
            for (int r = 0; r < 4; ++r)
                s_part[nt] = fmaf(D3[nt][r], inv[r], s_part[nt]);
    }

    // cross-g reduction (once, after all passes)
#pragma unroll
    for (int nt = 0; nt < 4; ++nt) {
        s_part[nt] += __shfl_xor(s_part[nt], 16, 64);
        s_part[nt] += __shfl_xor(s_part[nt], 32, 64);
    }
    uu_part += __shfl_xor(uu_part, 16, 64);
    uu_part += __shfl_xor(uu_part, 32, 64);

    if (g == 0) {
#pragma unroll
        for (int nt = 0; nt < 4; ++nt) sred[wv][nt * 16 + sl] = s_part[nt];
    }
    if (lane == 0) uured[wv] = uu_part * 0.0625f;
    __syncthreads();

    if (tid < 64) {
        const float t = sred[0][tid] + sred[1][tid] + sred[2][tid] + sred[3][tid];
        atomicAdd(&acc[tid], t);
    }
    if (tid == 0)
        atomicAdd(&acc[64], uured[0] + uured[1] + uured[2] + uured[3]);
}

__global__ void finalize_k(const float* __restrict__ acc, float* __restrict__ out)
{
    float s = acc[threadIdx.x];
    float d = s * s;
#pragma unroll
    for (int off = 32; off > 0; off >>= 1)
        d += __shfl_xor(d, off, 64);
    if (threadIdx.x == 0)
        out[0] = 0.5f * (d - acc[64]) / (float)NROWS;
}

extern "C" void kernel_launch(void* const* d_in, const int* in_sizes, int n_in,
                              void* d_out, int out_size, void* d_ws, size_t ws_size,
                              hipStream_t stream)
{
    const float* x  = (const float*)d_in[0];
    const float* W1 = (const float*)d_in[1];
    const float* b1 = (const float*)d_in[2];
    const float* W2 = (const float*)d_in[3];
    const float* b2 = (const float*)d_in[4];
    const float* W3 = (const float*)d_in[5];
    const float* b3 = (const float*)d_in[6];

    char* ws = (char*)d_ws;
    // layout: [acc 1024][w1f 24576][b1 384][b2 320][b3 256][w2f 15360][w3f 12288]
    float*          acc = (float*)ws;
    unsigned short* w1f = (unsigned short*)(ws + 1024);
    float*          b1p = (float*)(ws + 25600);
    float*          b2p = (float*)(ws + 25984);
    float*          b3p = (float*)(ws + 26304);
    unsigned short* w2f = (unsigned short*)(ws + 26560);
    unsigned short* w3f = (unsigned short*)(ws + 41920);

    hipMemsetAsync(acc, 0, 1024, stream);
    repack<<<52, 64, 0, stream>>>(W1, b1, W2, b2, W3, b3, w1f, w2f, w3f, b1p, b2p, b3p);
    // 512 blocks x 4 waves x 8 passes x 16 rows = 262144 rows
    mlp_main<<<NROWS / (4 * PASSES * 16), 256, 0, stream>>>(
        x, (const f32x4*)(ws + 1024), w2f, w3f, acc);
    finalize_k<<<1, 64, 0, stream>>>(acc, (float*)d_out);
}

// Round 15
// 53.183 us; speedup vs baseline: 1.7052x; 1.0324x over previous
//
#include <hip/hip_runtime.h>

typedef float  f32x4  __attribute__((ext_vector_type(4)));
typedef short  s16x8  __attribute__((ext_vector_type(8)));
typedef short  s16x4  __attribute__((ext_vector_type(4)));

#define NROWS (2048 * 128)
#define PASSES 8         // 16-row passes per wave; 512 blocks x 4 waves x 8 x 16
#define HS 104           // act LDS stride in shorts
#define EPSF 1e-8f

union Frag { s16x8 v; unsigned short u[8]; };

// fp32 -> bf16 RTNE (verified R3-R14, absmax 0.0)
__device__ __forceinline__ unsigned short f2bf(float f) {
    unsigned int u = __float_as_uint(f);
    u += 0x7fffu + ((u >> 16) & 1u);
    return (unsigned short)(u >> 16);
}

// ---------------------------------------------------------------------------
// Pre-kernel: repack weights (bit-identical to R14). The stored per-lane
// layout serves as BOTH B-frag (old use) and A-frag (new use: lane holds
// W[out = base + (l&15)][k = (l>>4)*8 + j]).
// ws layout: [acc 1024][w1f 24576][b1 384][b2 320][b3 256][w2f 15360][w3f 12288]
// ---------------------------------------------------------------------------
__global__ void repack(const float* __restrict__ W1, const float* __restrict__ b1,
                       const float* __restrict__ W2, const float* __restrict__ b2,
                       const float* __restrict__ W3, const float* __restrict__ b3,
                       unsigned short* __restrict__ w1f, unsigned short* __restrict__ w2f,
                       unsigned short* __restrict__ w3f,
                       float* __restrict__ b1p, float* __restrict__ b2p,
                       float* __restrict__ b3p)
{
    const int b = blockIdx.x;
    const int l = threadIdx.x;      // 64 threads
    const int g = l >> 4, sl = l & 15;

    if (b < 24) {                   // W1: nt = b>>2, ks = b&3
        const int nt = b >> 2, ks = b & 3;
        const int o = nt * 16 + sl, kb = ks * 32 + g * 8;
        s16x8 v;
#pragma unroll
        for (int j = 0; j < 8; ++j) v[j] = (short)f2bf(W1[o * 128 + kb + j]);
        *(s16x8*)&w1f[b * 512 + l * 8] = v;
    } else if (b < 39) {            // W2 (out padded 72->80)
        const int f = b - 24, nt = f / 3, ks = f % 3;
        const int o = nt * 16 + sl, kb = ks * 32 + g * 8;
        s16x8 v;
#pragma unroll
        for (int j = 0; j < 8; ++j)
            v[j] = (short)((o < 72) ? f2bf(W2[o * 96 + kb + j]) : 0);
        *(s16x8*)&w2f[f * 512 + l * 8] = v;
    } else if (b < 51) {            // W3 (k padded 72->96)
        const int f = b - 39, nt = f / 3, ks = f % 3;
        const int o = nt * 16 + sl, kb = ks * 32 + g * 8;
        s16x8 v;
#pragma unroll
        for (int j = 0; j < 8; ++j)
            v[j] = (short)((kb + j < 72) ? f2bf(W3[o * 72 + kb + j]) : 0);
        *(s16x8*)&w3f[f * 512 + l * 8] = v;
    } else {                        // biases, zero-padded
        for (int i = l; i < 240; i += 64) {
            if (i < 96)       b1p[i] = b1[i];
            else if (i < 176) { int o = i - 96; b2p[o] = (o < 72) ? b2[o] : 0.f; }
            else              b3p[i - 176] = b3[i - 176];
        }
    }
}

// ---------------------------------------------------------------------------
// Main. R14 + SWAPPED MFMA OPERANDS: D = W x h^T (W is the A operand; the
// repacked per-lane data already matches A-frag order). D mapping: lane
// (g,sl) holds f[out = nt*16+g*4+r][sample = sl] -> the 4 outs per register
// quad are CONTIGUOUS feats of one sample, so:
//  - act writes become 11 x ds_write_b64 (was 44 scattered ds_write_b16)
//  - epilogue: ||f||^2 lane-local + 2 shuffles (was 16); 1 rsqrt (was 4);
//    s-reduction hoisted out of the pass loop.
// x B-frag / act reads / pad zeroing keep R13/R14's verified per-lane
// addresses. Same MFMA count. +12 VGPR (s_part 4->16), still 2 waves/EU.
// ---------------------------------------------------------------------------
__global__ __launch_bounds__(256, 1)
void mlp_main(const float* __restrict__ x,
              const f32x4* __restrict__ w1src,          // W1 frags + biases (1596 x 16 B)
              const unsigned short* __restrict__ w2f,   // 15 frags (hoisted to regs)
              const unsigned short* __restrict__ w3f,   // 12 frags (hoisted to regs)
              float* __restrict__ acc /* [65]: s[64], uu */)
{
    __shared__ __align__(16) unsigned char  wb[25536];        // W1 frags | b1 | b2 | b3
    __shared__ __align__(16) float          xbuf[4][2048];    // 32 KB: 8 KB/wave x tile
    __shared__ __align__(16) unsigned short act[4][16][HS];   // 13.3 KB wave-private
    __shared__ float sred[4][64];
    __shared__ float uured[4];

    const unsigned short* w1L = (const unsigned short*)wb;    // 24 frags
    const float* b1L = (const float*)(wb + 24576);            // 96
    const float* b2L = b1L + 96;                              // 80
    const float* b3L = b1L + 176;                             // 64

    const int tid  = threadIdx.x;
    const int lane = tid & 63;
    const int wv   = tid >> 6;
    const int g    = lane >> 4;
    const int sl   = lane & 15;
    const int g4   = g * 4;
    const int wave_gid = blockIdx.x * 4 + wv;     // 0..2047; wave owns 128 rows

    // ---- async stage of pass p's 16-row x tile (8 KB), swizzled source ----
    auto stage = [&](int p) {
        const char* tb = (const char*)x
                       + ((size_t)wave_gid * 128 + (size_t)p * 16) * 512;
        float* dst = &xbuf[wv][0];
#pragma unroll
        for (int c = 0; c < 8; ++c) {
            const unsigned off = (unsigned)(c * 1024 + lane * 16);
            const unsigned so  = off ^ (((off >> 9) & 7u) << 4);
            __builtin_amdgcn_global_load_lds(
                (const __attribute__((address_space(1))) void*)(tb + so),
                (__attribute__((address_space(3))) void*)(dst + c * 256),
                16, 0, 0);
        }
    };

    stage(0);                                   // in flight during W1 staging

    // ---- stage W1 + biases to LDS (25536 B = 1596 f32x4) ----
    for (int i = tid; i < 1596; i += 256)
        ((f32x4*)wb)[i] = w1src[i];

    // ---- hoist W2/W3 fragments into registers (loop-invariant) ----
    Frag W2r[5][3], W3r[4][3];
#pragma unroll
    for (int nt = 0; nt < 5; ++nt)
#pragma unroll
        for (int ks = 0; ks < 3; ++ks)
            W2r[nt][ks].v = *(const s16x8*)&w2f[(nt * 3 + ks) * 512 + lane * 8];
#pragma unroll
    for (int nt = 0; nt < 4; ++nt)
#pragma unroll
        for (int ks = 0; ks < 3; ++ks)
            W3r[nt][ks].v = *(const s16x8*)&w3f[(nt * 3 + ks) * 512 + lane * 8];

    __syncthreads();                            // weights visible; stage(0) drained

    float uu_part = 0.f;
    float s_part[4][4];
#pragma unroll
    for (int nt = 0; nt < 4; ++nt)
#pragma unroll
        for (int r = 0; r < 4; ++r) s_part[nt][r] = 0.f;

#pragma unroll 1
    for (int p = 0; p < PASSES; ++p) {
        // wait for this pass's staged tile
        asm volatile("s_waitcnt vmcnt(0)" ::: "memory");
        __builtin_amdgcn_sched_barrier(0);

        // ---- read x from LDS (swizzled) -> regs, cvt to B-frags (samples) ----
        const char* xb = (const char*)&xbuf[wv][0];
        const unsigned sw = (unsigned)((sl & 7) << 4);
        f32x4 t[8];
#pragma unroll
        for (int ks = 0; ks < 4; ++ks)
#pragma unroll
            for (int h = 0; h < 2; ++h)
                t[ks * 2 + h] = *(const f32x4*)(
                    xb + sl * 512 + ks * 128 + (((unsigned)(g * 32 + h * 16)) ^ sw));
        Frag X1[4];
#pragma unroll
        for (int ks = 0; ks < 4; ++ks)
#pragma unroll
            for (int j = 0; j < 4; ++j) {
                X1[ks].u[j]     = f2bf(t[ks * 2 + 0][j]);
                X1[ks].u[4 + j] = f2bf(t[ks * 2 + 1][j]);
            }

        // buffer free: issue next pass's stage; overlaps compute below
        __builtin_amdgcn_sched_barrier(0);
        if (p + 1 < PASSES) stage(p + 1);

        // ========== layer 1: D1 = W1 x x^T  (W1 = A operand, from LDS) ==========
        f32x4 D1[6];
#pragma unroll
        for (int nt = 0; nt < 6; ++nt)
            D1[nt] = *(const f32x4*)&b1L[nt * 16 + g4];   // bias over out-quad
#pragma unroll
        for (int ks = 0; ks < 4; ++ks)
#pragma unroll
            for (int nt = 0; nt < 6; ++nt) {
                const s16x8 Wf = *(const s16x8*)&w1L[(nt * 4 + ks) * 512 + lane * 8];
                D1[nt] = __builtin_amdgcn_mfma_f32_16x16x32_bf16(Wf, X1[ks].v, D1[nt], 0, 0, 0);
            }
        // relu + contiguous b64 write: act[sample=sl][feat nt*16+g4 .. +3]
#pragma unroll
        for (int nt = 0; nt < 6; ++nt) {
            s16x4 q;
#pragma unroll
            for (int j = 0; j < 4; ++j) q[j] = (short)f2bf(fmaxf(D1[nt][j], 0.f));
            *(s16x4*)&act[wv][sl][nt * 16 + g4] = q;
        }

        // layer-2 B-frags: feats 0..95 of sample sl (unchanged addressing)
        Frag A2[3];
#pragma unroll
        for (int ks = 0; ks < 3; ++ks)
            A2[ks].v = *(const s16x8*)&act[wv][sl][ks * 32 + g * 8];

        // zero pad feats 80..95 for the h2 tile (read by L3 ks=2)
        {
            const s16x4 z = (s16x4){0, 0, 0, 0};
            *(s16x4*)&act[wv][sl][80 + g4] = z;
        }

        // ========== layer 2: D2 = W2 x h1^T (W2 from registers) ==========
        f32x4 D2[5];
#pragma unroll
        for (int nt = 0; nt < 5; ++nt)
            D2[nt] = *(const f32x4*)&b2L[nt * 16 + g4];
#pragma unroll
        for (int ks = 0; ks < 3; ++ks)
#pragma unroll
            for (int nt = 0; nt < 5; ++nt)
                D2[nt] = __builtin_amdgcn_mfma_f32_16x16x32_bf16(W2r[nt][ks].v, A2[ks].v, D2[nt], 0, 0, 0);
#pragma unroll
        for (int nt = 0; nt < 5; ++nt) {
            s16x4 q;
#pragma unroll
            for (int j = 0; j < 4; ++j) q[j] = (short)f2bf(fmaxf(D2[nt][j], 0.f));
            *(s16x4*)&act[wv][sl][nt * 16 + g4] = q;
        }

        // layer-3 B-frags: h2 feats 0..95 (72..95 structurally zero)
        Frag A3[3];
#pragma unroll
        for (int ks = 0; ks < 3; ++ks)
            A3[ks].v = *(const s16x8*)&act[wv][sl][ks * 32 + g * 8];

        // ========== layer 3: D3 = W3 x h2^T (W3 from registers) ==========
        f32x4 D3[4];
#pragma unroll
        for (int nt = 0; nt < 4; ++nt)
            D3[nt] = *(const f32x4*)&b3L[nt * 16 + g4];
#pragma unroll
        for (int ks = 0; ks < 3; ++ks)
#pragma unroll
            for (int nt = 0; nt < 4; ++nt)
                D3[nt] = __builtin_amdgcn_mfma_f32_16x16x32_bf16(W3r[nt][ks].v, A3[ks].v, D3[nt], 0, 0, 0);

        // ===== epilogue (swapped): lane (g,sl) holds 16 outs of sample sl =====
        float ff = 0.f;
#pragma unroll
        for (int nt = 0; nt < 4; ++nt)
#pragma unroll
            for (int r = 0; r < 4; ++r)
                ff = fmaf(D3[nt][r], D3[nt][r], ff);
        ff += __shfl_xor(ff, 16, 64);           // reduce over g: full ||f[sl]||^2
        ff += __shfl_xor(ff, 32, 64);
        const float inv = 1.f / fmaxf(sqrtf(ff), EPSF);
        uu_part = fmaf(ff * inv, inv, uu_part); // x4 dup over g
#pragma unroll
        for (int nt = 0; nt < 4; ++nt)
#pragma unroll
            for (int r = 0; r < 4; ++r)
                s_part[nt][r] = fmaf(D3[nt][r], inv, s_part[nt][r]);
    }

    // ---- once per wave: s over sl lanes; uu over all lanes ----
#pragma unroll
    for (int nt = 0; nt < 4; ++nt)
#pragma unroll
        for (int r = 0; r < 4; ++r) {
            s_part[nt][r] += __shfl_xor(s_part[nt][r], 1, 64);
            s_part[nt][r] += __shfl_xor(s_part[nt][r], 2, 64);
            s_part[nt][r] += __shfl_xor(s_part[nt][r], 4, 64);
            s_part[nt][r] += __shfl_xor(s_part[nt][r], 8, 64);
        }
#pragma unroll
    for (int off = 1; off < 64; off <<= 1)
        uu_part += __shfl_xor(uu_part, off, 64);

    if (sl == 0) {                 // 4 lanes (g=0..3): s[out = nt*16+g4+r]
#pragma unroll
        for (int nt = 0; nt < 4; ++nt) {
            f32x4 v = {s_part[nt][0], s_part[nt][1], s_part[nt][2], s_part[nt][3]};
            *(f32x4*)&sred[wv][nt * 16 + g4] = v;
        }
    }
    if (lane == 0) uured[wv] = uu_part * 0.25f;   // / 4 dup over g
    __syncthreads();

    if (tid < 64) {
        const float t2 = sred[0][tid] + sred[1][tid] + sred[2][tid] + sred[3][tid];
        atomicAdd(&acc[tid], t2);
    }
    if (tid == 0)
        atomicAdd(&acc[64], uured[0] + uured[1] + uured[2] + uured[3]);
}

__global__ void finalize_k(const float* __restrict__ acc, float* __restrict__ out)
{
    float s = acc[threadIdx.x];
    float d = s * s;
#pragma unroll
    for (int off = 32; off > 0; off >>= 1)
        d += __shfl_xor(d, off, 64);
    if (threadIdx.x == 0)
        out[0] = 0.5f * (d - acc[64]) / (float)NROWS;
}

extern "C" void kernel_launch(void* const* d_in, const int* in_sizes, int n_in,
                              void* d_out, int out_size, void* d_ws, size_t ws_size,
                              hipStream_t stream)
{
    const float* x  = (const float*)d_in[0];
    const float* W1 = (const float*)d_in[1];
    const float* b1 = (const float*)d_in[2];
    const float* W2 = (const float*)d_in[3];
    const float* b2 = (const float*)d_in[4];
    const float* W3 = (const float*)d_in[5];
    const float* b3 = (const float*)d_in[6];

    char* ws = (char*)d_ws;
    // layout: [acc 1024][w1f 24576][b1 384][b2 320][b3 256][w2f 15360][w3f 12288]
    float*          acc = (float*)ws;
    unsigned short* w1f = (unsigned short*)(ws + 1024);
    float*          b1p = (float*)(ws + 25600);
    float*          b2p = (float*)(ws + 25984);
    float*          b3p = (float*)(ws + 26304);
    unsigned short* w2f = (unsigned short*)(ws + 26560);
    unsigned short* w3f = (unsigned short*)(ws + 41920);

    hipMemsetAsync(acc, 0, 1024, stream);
    repack<<<52, 64, 0, stream>>>(W1, b1, W2, b2, W3, b3, w1f, w2f, w3f, b1p, b2p, b3p);
    // 512 blocks x 4 waves x 8 passes x 16 rows = 262144 rows
    mlp_main<<<NROWS / (4 * PASSES * 16), 256, 0, stream>>>(
        x, (const f32x4*)(ws + 1024), w2f, w3f, acc);
    finalize_k<<<1, 64, 0, stream>>>(acc, (float*)d_out);
}